// Round 10
// baseline (198.528 us; speedup 1.0000x reference)
//
#include <hip/hip_runtime.h>
#include <math.h>

// ComplexEMA fused single-kernel (R9, third submission -- Rounds 8/9 both
// died to container-level infra failures; kernel re-audited for faults:
// all LDS/global indices in-bounds, unconditional barriers, fixed trip
// counts -- nothing here can hang or fault. Resubmitting so the icache
// A/B finally runs).
// y[b,d,t] = Re(sum_n gam_dn * h_dn[t]) + omega_d * x[b,d,t]
// h[t] = q*h[t-1] + p*x[t];  u = h/p:  u' = q*u + x, gam' = p*gam.
//
// Theory: R4-R8 (95-110us) are all FULLY UNROLLED over the 63 recurrence
// steps -> ~8-10k instructions (~70-80KB) vs 32KB L1I. Issue work is only
// ~34us but VALU-busy time is ~68us and dur 104us: instruction-fetch stalls.
// R9 rolls the j-loops (runtime-indexed x via conflict-free SoA LDS, so no
// register-array scratch), the scan rounds, and the squarings -> ~7KB code.
//
// One block (128 threads = 2 waves) per (b,d) row; thread owns a 32-step
// chunk. x burst-loaded (8 dwordx4 = 128B/lane) then staged to LDS SoA
// xls[j][tid] (lane-consecutive -> conflict-free). Phase 1: rolled local
// recurrence (scalar complex: 4 FMA/mode/step). Scan: rolled 6-round
// __shfl_up Hillis-Steele (A=q^32 doubling), W=A^(llane+1) on wave 1, one
// LDS publish + barrier. Phase 3: rolled recurrence from exclusive prefix,
// y overwrites x in-place in LDS (same-thread slots), epilogue bursts y out.

constexpr int kD = 2048, kN = 16, kB = 2, kL = 4096;
constexpr int kT  = 128;            // threads (= chunks) per row, 2 waves
constexpr int kCH = kL / kT;        // 32 timesteps per thread
constexpr float kSCALE = 0.25f;     // sqrt(1/16)

__global__ __launch_bounds__(kT, 2) void fused_kernel(
    const float* __restrict__ x,     const float* __restrict__ alpha,
    const float* __restrict__ delta, const float* __restrict__ theta,
    const float* __restrict__ gamma, const float* __restrict__ omega,
    float* __restrict__ y,           float* __restrict__ hout)
{
    __shared__ float xls[kCH * kT];        // SoA x (then y) stage, 16 KB
    __shared__ float cqr[kN], cqi[kN], cgr[kN], cgi[kN], cp[kN];
    __shared__ float pubr[kN], pubi[kN];   // wave-0 final state publish

    const int row   = blockIdx.x;          // b*kD + d
    const int d     = row & (kD - 1);
    const int tid   = threadIdx.x;
    const int llane = tid & 63;
    const bool w1   = (tid >= 64);

    // --- burst-load 32 x samples (8 back-to-back dwordx4 = 128 B/lane)
    const float4* xp = (const float4*)(x + (size_t)row * kL + (size_t)tid * kCH);
    float4 tb[8];
#pragma unroll
    for (int k = 0; k < 8; k++) tb[k] = xp[k];

    // --- coefficients (threads 0..15, one n each)
    if (tid < kN) {
        int n = tid, i = d * kN + n;
        float p  = 1.0f / (1.0f + expf(-alpha[i]));
        float dd = 1.0f / (1.0f + expf(-delta[i]));
        float th = 1.0f / (1.0f + expf(-theta[d]));
        float phi = (float)(n + 1) * th * 0.39269908169872414f;  // 2*pi/16
        float r = 1.0f - p * dd;
        float s, c;
        sincosf(phi, &s, &c);
        cqr[n] = r * c;
        cqi[n] = r * s;
        cgr[n] = p * kSCALE * gamma[2 * i];
        cgi[n] = -(p * kSCALE * gamma[2 * i + 1]);
        cp[n]  = p;
    }

    // --- stage x to SoA LDS (per-inst addresses lane-consecutive)
#pragma unroll
    for (int k = 0; k < 8; k++) {
        xls[(4 * k + 0) * kT + tid] = tb[k].x;
        xls[(4 * k + 1) * kT + tid] = tb[k].y;
        xls[(4 * k + 2) * kT + tid] = tb[k].z;
        xls[(4 * k + 3) * kT + tid] = tb[k].w;
    }
    __syncthreads();                       // barrier #1 (coeffs + x stage)

    // --- coefficient registers (scalar): 32 VGPRs
    float qr[kN], qi[kN];
#pragma unroll
    for (int n = 0; n < kN; n++) { qr[n] = cqr[n]; qi[n] = cqi[n]; }

    // --- phase 1: rolled local recurrence from zero (first step peeled:
    //     u = (x0, 0)). 4 FMA/mode/step, 16-way ILP.
    float ur[kN], ui[kN];
    {
        float x0 = xls[tid];
#pragma unroll
        for (int n = 0; n < kN; n++) { ur[n] = x0; ui[n] = 0.0f; }
    }
#pragma unroll 1
    for (int j = 1; j < kCH; j++) {
        float xj = xls[j * kT + tid];
#pragma unroll
        for (int n = 0; n < kN; n++) {
            float nr = __builtin_fmaf(qr[n], ur[n],
                       __builtin_fmaf(-qi[n], ui[n], xj));
            float ni = __builtin_fmaf(qr[n], ui[n], qi[n] * ur[n]);
            ur[n] = nr; ui[n] = ni;
        }
    }

    // --- A = q^32 via 5 rolled complex squarings
    float mr[kN], mi[kN];
#pragma unroll
    for (int n = 0; n < kN; n++) { mr[n] = qr[n]; mi[n] = qi[n]; }
#pragma unroll 1
    for (int k = 0; k < 5; k++) {
#pragma unroll
        for (int n = 0; n < kN; n++) {
            float t = __builtin_fmaf(mr[n], mr[n], -(mi[n] * mi[n]));
            mi[n] = 2.0f * mr[n] * mi[n];
            mr[n] = t;
        }
    }

    // --- rolled wave-synchronous Hillis-Steele (6 rounds).
    //     Wave 1 accumulates W = A^(llane+1).
    float Wr[kN], Wi[kN];
#pragma unroll
    for (int n = 0; n < kN; n++) { Wr[n] = mr[n]; Wi[n] = mi[n]; }
#pragma unroll 1
    for (int k = 0; k < 6; k++) {
        const int s = 1 << k;
#pragma unroll
        for (int n = 0; n < kN; n++) {
            float tr = __shfl_up(ur[n], (unsigned)s, 64);
            float ti = __shfl_up(ui[n], (unsigned)s, 64);
            if (llane >= s) {
                ur[n] = __builtin_fmaf(mr[n], tr,
                        __builtin_fmaf(-mi[n], ti, ur[n]));
                ui[n] = __builtin_fmaf(mr[n], ti,
                        __builtin_fmaf( mi[n], tr, ui[n]));
            }
        }
        if (w1 && (llane & s)) {
#pragma unroll
            for (int n = 0; n < kN; n++) {
                float wr = Wr[n], wi = Wi[n];
                Wr[n] = __builtin_fmaf(wr, mr[n], -(wi * mi[n]));
                Wi[n] = __builtin_fmaf(wr, mi[n],  wi * mr[n]);
            }
        }
#pragma unroll
        for (int n = 0; n < kN; n++) {
            float t = __builtin_fmaf(mr[n], mr[n], -(mi[n] * mi[n]));
            mi[n] = 2.0f * mr[n] * mi[n];
            mr[n] = t;
        }
    }

    // --- cross-wave combine: publish wave-0 lane-63 state, one barrier.
    if (tid == 63) {
#pragma unroll
        for (int n = 0; n < kN; n++) { pubr[n] = ur[n]; pubi[n] = ui[n]; }
    }
    __syncthreads();                       // barrier #2
    if (w1) {
#pragma unroll
        for (int n = 0; n < kN; n++) {
            float pr = pubr[n], pi = pubi[n];
            ur[n] = __builtin_fmaf(Wr[n], pr,
                    __builtin_fmaf(-Wi[n], pi, ur[n]));
            ui[n] = __builtin_fmaf(Wr[n], pi,
                    __builtin_fmaf( Wi[n], pr, ui[n]));
        }
    }

    // --- final state (tid 127 inclusive) -> hout, h = p*u
    if (tid == kT - 1) {
        float4* hp = (float4*)(hout + (size_t)row * (kN * 2));
#pragma unroll
        for (int n = 0; n < kN; n += 2)
            hp[n >> 1] = make_float4(cp[n] * ur[n],         cp[n] * ui[n],
                                     cp[n + 1] * ur[n + 1], cp[n + 1] * ui[n + 1]);
    }

    // --- exclusive prefix: shift down one lane; wave-1 lane 0 takes the
    //     published wave-0 final; thread 0 takes zero.
#pragma unroll
    for (int n = 0; n < kN; n++) {
        float pr = __shfl_up(ur[n], 1, 64);
        float pi = __shfl_up(ui[n], 1, 64);
        ur[n] = pr; ui[n] = pi;
    }
    if (llane == 0) {
#pragma unroll
        for (int n = 0; n < kN; n++) {
            ur[n] = (tid == 0) ? 0.0f : pubr[n];
            ui[n] = (tid == 0) ? 0.0f : pubi[n];
        }
    }

    // --- phase 3: rolled recurrence from correct init; y overwrites x
    //     in-place in LDS (each thread touches only its own slots).
    float gr[kN], gi[kN];
#pragma unroll
    for (int n = 0; n < kN; n++) { gr[n] = cgr[n]; gi[n] = cgi[n]; }
    const float om = omega[d];

#pragma unroll 1
    for (int j = 0; j < kCH; j++) {
        const int off = j * kT + tid;
        float xj = xls[off];
        float acc0 = om * xj, acc1 = 0.0f, acc2 = 0.0f, acc3 = 0.0f;
#pragma unroll
        for (int n = 0; n < kN; n += 4) {
            float nr, ni;
            nr = __builtin_fmaf(qr[n], ur[n], __builtin_fmaf(-qi[n], ui[n], xj));
            ni = __builtin_fmaf(qr[n], ui[n], qi[n] * ur[n]);
            ur[n] = nr; ui[n] = ni;
            acc0 = __builtin_fmaf(gr[n], nr, __builtin_fmaf(gi[n], ni, acc0));
            nr = __builtin_fmaf(qr[n+1], ur[n+1], __builtin_fmaf(-qi[n+1], ui[n+1], xj));
            ni = __builtin_fmaf(qr[n+1], ui[n+1], qi[n+1] * ur[n+1]);
            ur[n+1] = nr; ui[n+1] = ni;
            acc1 = __builtin_fmaf(gr[n+1], nr, __builtin_fmaf(gi[n+1], ni, acc1));
            nr = __builtin_fmaf(qr[n+2], ur[n+2], __builtin_fmaf(-qi[n+2], ui[n+2], xj));
            ni = __builtin_fmaf(qr[n+2], ui[n+2], qi[n+2] * ur[n+2]);
            ur[n+2] = nr; ui[n+2] = ni;
            acc2 = __builtin_fmaf(gr[n+2], nr, __builtin_fmaf(gi[n+2], ni, acc2));
            nr = __builtin_fmaf(qr[n+3], ur[n+3], __builtin_fmaf(-qi[n+3], ui[n+3], xj));
            ni = __builtin_fmaf(qr[n+3], ui[n+3], qi[n+3] * ur[n+3]);
            ur[n+3] = nr; ui[n+3] = ni;
            acc3 = __builtin_fmaf(gr[n+3], nr, __builtin_fmaf(gi[n+3], ni, acc3));
        }
        xls[off] = (acc0 + acc1) + (acc2 + acc3);
    }

    // --- epilogue: read back own y values, burst-store (8 dwordx4/lane).
    //     No barrier needed: each thread reads only slots it wrote.
    float4* yp = (float4*)(y + (size_t)row * kL + (size_t)tid * kCH);
#pragma unroll
    for (int k = 0; k < 8; k++) {
        float4 v;
        v.x = xls[(4 * k + 0) * kT + tid];
        v.y = xls[(4 * k + 1) * kT + tid];
        v.z = xls[(4 * k + 2) * kT + tid];
        v.w = xls[(4 * k + 3) * kT + tid];
        yp[k] = v;
    }
}

extern "C" void kernel_launch(void* const* d_in, const int* in_sizes, int n_in,
                              void* d_out, int out_size, void* d_ws, size_t ws_size,
                              hipStream_t stream) {
    const float* x     = (const float*)d_in[0];
    const float* alpha = (const float*)d_in[1];
    const float* delta = (const float*)d_in[2];
    const float* theta = (const float*)d_in[3];
    const float* gamma = (const float*)d_in[4];
    const float* omega = (const float*)d_in[5];
    float* y    = (float*)d_out;
    float* hout = y + (size_t)kB * kD * kL;      // (B,D,N,2) after y

    fused_kernel<<<kB * kD, kT, 0, stream>>>(x, alpha, delta, theta, gamma,
                                             omega, y, hout);
}

// Round 11
// 179.516 us; speedup vs baseline: 1.1059x; 1.1059x over previous
//
#include <hip/hip_runtime.h>
#include <math.h>

// ComplexEMA fused single-kernel (R11 = R4/R7 structure, MODE-PACKED math).
// y[b,d,t] = Re(sum_n gam_dn * h_dn[t]) + omega_d * x[b,d,t]
// h[t] = q*h[t-1] + p*x[t];  u = h/p:  u' = q*u + x, gam' = p*gam.
//
// Evidence: R4-R9 are VALU-ISSUE-bound (busy-time R4 56us / R7 66us / R9
// 87us tracks duration 95/106/121; occupancy & scan-style second-order).
// Old (re,im) v2 packing needs a half-swap per packed FMA (op_sel or movs);
// R9's scalar form needs 4 FMA/mode/step. R11 packs TWO MODES per v2:
// u2r[k]=(ur[2k],ur[2k+1]), u2i[k] likewise -> complex recurrence is pure
// elementwise: nr2 = fma(q2r,u2r, fma(-q2i,u2i,xj)); ni2 = fma(q2r,u2i,
// q2i*u2r). 2 packed insts/mode/step, ZERO swizzles. Phase 3 adds 1
// packed inst/mode for the gamma-accumulate. Code size also ~halves.
//
// Structure (best measured): one block (128 thr = 2 waves) per (b,d) row,
// x burst-loaded to REGISTERS once (8 dwordx4 = 128B/lane) and kept live;
// fully unrolled phases (R9 showed rolling costs +20us); 6-round __shfl_up
// Hillis-Steele scan (A=q^32 doubling, W=A^(llane+1) on wave 1); ONE LDS
// publish + 2 barriers total; 128B/lane burst y stores.

constexpr int kD = 2048, kN = 16, kB = 2, kL = 4096;
constexpr int kT  = 128;            // threads (= chunks) per row, 2 waves
constexpr int kCH = kL / kT;        // 32 timesteps per thread
constexpr int kP  = kN / 2;         // 8 mode-pairs (packed)
constexpr float kSCALE = 0.25f;     // sqrt(1/16)

typedef float v2 __attribute__((ext_vector_type(2)));

static __device__ __forceinline__ v2 mkv2(float a, float b) {
    v2 r; r.x = a; r.y = b; return r;
}
static __device__ __forceinline__ v2 vfma(v2 a, v2 b, v2 c) {
    return __builtin_elementwise_fma(a, b, c);
}

__global__ __launch_bounds__(kT, 2) void fused_kernel(
    const float* __restrict__ x,     const float* __restrict__ alpha,
    const float* __restrict__ delta, const float* __restrict__ theta,
    const float* __restrict__ gamma, const float* __restrict__ omega,
    float* __restrict__ y,           float* __restrict__ hout)
{
    __shared__ float cqr[kN], cqi[kN], cgr[kN], cgi[kN], cp[kN];
    __shared__ float pubr[kN], pubi[kN];   // wave-0 final state publish

    const int row   = blockIdx.x;          // b*kD + d
    const int d     = row & (kD - 1);
    const int tid   = threadIdx.x;
    const int llane = tid & 63;
    const bool w1   = (tid >= 64);

    // --- burst-load 32 x samples to registers (8 back-to-back dwordx4 =
    //     128 B/lane); latency hides under coeff compute.
    const float4* xp = (const float4*)(x + (size_t)row * kL + (size_t)tid * kCH);
    float xs[kCH];
    {
        float4 tb[8];
#pragma unroll
        for (int k = 0; k < 8; k++) tb[k] = xp[k];
#pragma unroll
        for (int k = 0; k < 8; k++) {
            xs[4*k+0] = tb[k].x; xs[4*k+1] = tb[k].y;
            xs[4*k+2] = tb[k].z; xs[4*k+3] = tb[k].w;
        }
    }

    // --- coefficients (threads 0..15, one n each)
    if (tid < kN) {
        int n = tid, i = d * kN + n;
        float p  = 1.0f / (1.0f + expf(-alpha[i]));
        float dd = 1.0f / (1.0f + expf(-delta[i]));
        float th = 1.0f / (1.0f + expf(-theta[d]));
        float phi = (float)(n + 1) * th * 0.39269908169872414f;  // 2*pi/16
        float r = 1.0f - p * dd;
        float s, c;
        sincosf(phi, &s, &c);
        cqr[n] = r * c;
        cqi[n] = r * s;
        cgr[n] = p * kSCALE * gamma[2 * i];
        cgi[n] = -(p * kSCALE * gamma[2 * i + 1]);
        cp[n]  = p;
    }
    __syncthreads();                       // barrier #1 (coeff visibility)

    // --- phase 1: unrolled local recurrence from zero (first step peeled:
    //     u = (x0, 0)). Mode-packed: 4 packed ops per pair per step.
    v2 u2r[kP], u2i[kP];
    {
        v2 q2r[kP], q2i[kP];
#pragma unroll
        for (int k = 0; k < kP; k++) {
            q2r[k] = mkv2(cqr[2*k], cqr[2*k+1]);
            q2i[k] = mkv2(cqi[2*k], cqi[2*k+1]);
        }
#pragma unroll
        for (int k = 0; k < kP; k++) {
            u2r[k] = mkv2(xs[0], xs[0]);
            u2i[k] = mkv2(0.0f, 0.0f);
        }
#pragma unroll
        for (int j = 1; j < kCH; j++) {
            v2 xj2 = mkv2(xs[j], xs[j]);
#pragma unroll
            for (int k = 0; k < kP; k++) {
                v2 t  = vfma(-q2i[k], u2i[k], xj2);
                v2 nr = vfma( q2r[k], u2r[k], t);
                v2 s  = q2i[k] * u2r[k];
                v2 ni = vfma( q2r[k], u2i[k], s);
                u2r[k] = nr; u2i[k] = ni;
            }
        }
    }   // q2 dead here (rebuilt from LDS for phase 3)

    // --- A = q^32 via 5 packed complex squarings
    v2 m2r[kP], m2i[kP];
#pragma unroll
    for (int k = 0; k < kP; k++) {
        m2r[k] = mkv2(cqr[2*k], cqr[2*k+1]);
        m2i[k] = mkv2(cqi[2*k], cqi[2*k+1]);
    }
#pragma unroll
    for (int s = 0; s < 5; s++) {
#pragma unroll
        for (int k = 0; k < kP; k++) {
            v2 t = vfma(m2r[k], m2r[k], -(m2i[k] * m2i[k]));
            v2 im = m2r[k] * m2i[k];
            m2i[k] = im + im;
            m2r[k] = t;
        }
    }

    // --- 6-round wave-synchronous Hillis-Steele (in-register).
    //     Wave 1 accumulates W = A^(llane+1) for the cross-wave fix.
    v2 W2r[kP], W2i[kP];
#pragma unroll
    for (int k = 0; k < kP; k++) { W2r[k] = m2r[k]; W2i[k] = m2i[k]; }
#pragma unroll
    for (int r = 0; r < 6; r++) {
        const int s = 1 << r;
#pragma unroll
        for (int k = 0; k < kP; k++) {
            float trx = __shfl_up(u2r[k].x, (unsigned)s, 64);
            float trY = __shfl_up(u2r[k].y, (unsigned)s, 64);
            float tix = __shfl_up(u2i[k].x, (unsigned)s, 64);
            float tiY = __shfl_up(u2i[k].y, (unsigned)s, 64);
            if (llane >= s) {
                v2 tr = mkv2(trx, trY), ti = mkv2(tix, tiY);
                v2 a = vfma(-m2i[k], ti, u2r[k]);
                u2r[k] = vfma(m2r[k], tr, a);
                v2 b = vfma(m2i[k], tr, u2i[k]);
                u2i[k] = vfma(m2r[k], ti, b);
            }
        }
        if (w1 && (llane & s)) {
#pragma unroll
            for (int k = 0; k < kP; k++) {
                v2 a = vfma(W2r[k], m2r[k], -(W2i[k] * m2i[k]));
                v2 b = vfma(W2r[k], m2i[k],  W2i[k] * m2r[k]);
                W2r[k] = a; W2i[k] = b;
            }
        }
        if (r < 5) {
#pragma unroll
            for (int k = 0; k < kP; k++) {
                v2 t = vfma(m2r[k], m2r[k], -(m2i[k] * m2i[k]));
                v2 im = m2r[k] * m2i[k];
                m2i[k] = im + im;
                m2r[k] = t;
            }
        }
    }

    // --- cross-wave combine: publish wave-0 lane-63 state, one barrier.
    if (tid == 63) {
#pragma unroll
        for (int k = 0; k < kP; k++) {
            pubr[2*k]   = u2r[k].x; pubr[2*k+1] = u2r[k].y;
            pubi[2*k]   = u2i[k].x; pubi[2*k+1] = u2i[k].y;
        }
    }
    __syncthreads();                       // barrier #2
    if (w1) {
#pragma unroll
        for (int k = 0; k < kP; k++) {
            v2 pr = mkv2(pubr[2*k], pubr[2*k+1]);
            v2 pi = mkv2(pubi[2*k], pubi[2*k+1]);
            v2 a = vfma(-W2i[k], pi, u2r[k]);
            u2r[k] = vfma(W2r[k], pr, a);
            v2 b = vfma(W2i[k], pr, u2i[k]);
            u2i[k] = vfma(W2r[k], pi, b);
        }
    }

    // --- final state (tid 127 inclusive) -> hout, h = p*u
    if (tid == kT - 1) {
        float4* hp = (float4*)(hout + (size_t)row * (kN * 2));
#pragma unroll
        for (int k = 0; k < kP; k++)
            hp[k] = make_float4(cp[2*k]   * u2r[k].x, cp[2*k]   * u2i[k].x,
                                cp[2*k+1] * u2r[k].y, cp[2*k+1] * u2i[k].y);
    }

    // --- exclusive prefix: shift down one lane; wave-1 lane 0 takes the
    //     published wave-0 final; thread 0 takes zero.
#pragma unroll
    for (int k = 0; k < kP; k++) {
        float a = __shfl_up(u2r[k].x, 1, 64);
        float b = __shfl_up(u2r[k].y, 1, 64);
        float c = __shfl_up(u2i[k].x, 1, 64);
        float e = __shfl_up(u2i[k].y, 1, 64);
        u2r[k] = mkv2(a, b);
        u2i[k] = mkv2(c, e);
    }
    if (llane == 0) {
#pragma unroll
        for (int k = 0; k < kP; k++) {
            u2r[k] = (tid == 0) ? mkv2(0.0f, 0.0f)
                                : mkv2(pubr[2*k], pubr[2*k+1]);
            u2i[k] = (tid == 0) ? mkv2(0.0f, 0.0f)
                                : mkv2(pubi[2*k], pubi[2*k+1]);
        }
    }

    // --- phase 3: rebuild packed coeffs, re-run chunk, emit y.
    v2 q2r[kP], q2i[kP], g2r[kP], g2i[kP];
#pragma unroll
    for (int k = 0; k < kP; k++) {
        q2r[k] = mkv2(cqr[2*k], cqr[2*k+1]);
        q2i[k] = mkv2(cqi[2*k], cqi[2*k+1]);
        g2r[k] = mkv2(cgr[2*k], cgr[2*k+1]);
        g2i[k] = mkv2(cgi[2*k], cgi[2*k+1]);
    }
    const float om = omega[d];

    float ys[kCH];
#pragma unroll
    for (int j = 0; j < kCH; j++) {
        float xj = xs[j];
        v2 xj2 = mkv2(xj, xj);
        v2 acc0 = mkv2(0.0f, 0.0f), acc1 = mkv2(0.0f, 0.0f);
        v2 acc2 = mkv2(0.0f, 0.0f), acc3 = mkv2(0.0f, 0.0f);
#pragma unroll
        for (int k = 0; k < kP; k += 4) {
            v2 t, s, nr, ni;
            t  = vfma(-q2i[k],   u2i[k],   xj2);
            nr = vfma( q2r[k],   u2r[k],   t);
            s  = q2i[k] * u2r[k];
            ni = vfma( q2r[k],   u2i[k],   s);
            u2r[k] = nr; u2i[k] = ni;
            acc0 = vfma(g2r[k], nr, acc0);
            acc0 = vfma(g2i[k], ni, acc0);
            t  = vfma(-q2i[k+1], u2i[k+1], xj2);
            nr = vfma( q2r[k+1], u2r[k+1], t);
            s  = q2i[k+1] * u2r[k+1];
            ni = vfma( q2r[k+1], u2i[k+1], s);
            u2r[k+1] = nr; u2i[k+1] = ni;
            acc1 = vfma(g2r[k+1], nr, acc1);
            acc1 = vfma(g2i[k+1], ni, acc1);
            t  = vfma(-q2i[k+2], u2i[k+2], xj2);
            nr = vfma( q2r[k+2], u2r[k+2], t);
            s  = q2i[k+2] * u2r[k+2];
            ni = vfma( q2r[k+2], u2i[k+2], s);
            u2r[k+2] = nr; u2i[k+2] = ni;
            acc2 = vfma(g2r[k+2], nr, acc2);
            acc2 = vfma(g2i[k+2], ni, acc2);
            t  = vfma(-q2i[k+3], u2i[k+3], xj2);
            nr = vfma( q2r[k+3], u2r[k+3], t);
            s  = q2i[k+3] * u2r[k+3];
            ni = vfma( q2r[k+3], u2i[k+3], s);
            u2r[k+3] = nr; u2i[k+3] = ni;
            acc3 = vfma(g2r[k+3], nr, acc3);
            acc3 = vfma(g2i[k+3], ni, acc3);
        }
        v2 sm = (acc0 + acc1) + (acc2 + acc3);
        ys[j] = sm.x + sm.y + om * xj;
    }

    // burst stores (8 back-to-back dwordx4 = 128 B/lane)
    float4* yp = (float4*)(y + (size_t)row * kL + (size_t)tid * kCH);
#pragma unroll
    for (int k = 0; k < 8; k++)
        yp[k] = make_float4(ys[4*k+0], ys[4*k+1], ys[4*k+2], ys[4*k+3]);
}

extern "C" void kernel_launch(void* const* d_in, const int* in_sizes, int n_in,
                              void* d_out, int out_size, void* d_ws, size_t ws_size,
                              hipStream_t stream) {
    const float* x     = (const float*)d_in[0];
    const float* alpha = (const float*)d_in[1];
    const float* delta = (const float*)d_in[2];
    const float* theta = (const float*)d_in[3];
    const float* gamma = (const float*)d_in[4];
    const float* omega = (const float*)d_in[5];
    float* y    = (float*)d_out;
    float* hout = y + (size_t)kB * kD * kL;      // (B,D,N,2) after y

    fused_kernel<<<kB * kD, kT, 0, stream>>>(x, alpha, delta, theta, gamma,
                                             omega, y, hout);
}